// Round 9
// baseline (138.377 us; speedup 1.0000x reference)
//
#include <hip/hip_runtime.h>
#include <math.h>

#define T_DIM 4096
#define H_DIM 2048
#define N_DIM 1024
#define N2    2048           // 2*N (concat re/im) == H
#define KK    2048           // full K of both GEMMs
#define CHUNK 64
#define NCHUNK (T_DIM / CHUNK)
#define NTK   16             // K-tiles per block: K-half (1024) / BK (64)

using u16    = unsigned short;
using u16x4  = __attribute__((ext_vector_type(4))) u16;
using u16x8  = __attribute__((ext_vector_type(8))) u16;
using bf16x8 = __attribute__((ext_vector_type(8))) short;
using f32x4  = __attribute__((ext_vector_type(4))) float;

typedef const __attribute__((address_space(1))) u16 glob_u16;
typedef __attribute__((address_space(3))) u16 lds_u16;

__device__ inline void gload16(const u16* g, u16* l) {
    // async global->LDS: per-lane global src, wave-uniform LDS base + lane*16
    __builtin_amdgcn_global_load_lds((glob_u16*)g, (lds_u16*)l, 16, 0, 0);
}

__device__ inline u16 f2bf(float x) {   // RNE fp32->bf16
    unsigned u = __builtin_bit_cast(unsigned, x);
    u += 0x7fffu + ((u >> 16) & 1u);
    return (u16)(u >> 16);
}
__device__ inline float bf2f(u16 x) {
    return __builtin_bit_cast(float, (unsigned)x << 16);
}

// ---------------------------------------------------------------------------
// Merged conversion kernel (R8-verified): U / Bcat / Ccat regions
// ---------------------------------------------------------------------------
__global__ __launch_bounds__(256) void cvt_all_k(
    const float* __restrict__ U, const float* __restrict__ Bre,
    const float* __restrict__ Bim, const float* __restrict__ glog,
    const float* __restrict__ Cre, const float* __restrict__ Cim,
    u16* __restrict__ Ubf, u16* __restrict__ Bcat, u16* __restrict__ Ccat)
{
    int bid = blockIdx.x;
    if (bid < 8192) {
        size_t i = ((size_t)bid * 256 + threadIdx.x) * 4;
        float4 v = *(const float4*)(U + i);
        u16x4 o = { f2bf(v.x), f2bf(v.y), f2bf(v.z), f2bf(v.w) };
        *(u16x4*)(Ubf + i) = o;
    } else if (bid < 12288) {
        size_t i = ((size_t)(bid - 8192) * 256 + threadIdx.x) * 4;
        int n = (int)(i >> 11);
        size_t h = i & 2047;
        int nn = n & (N_DIM - 1);
        float g = expf(glog[nn]);
        const float* src = (n < N_DIM ? Bre : Bim) + (size_t)nn * H_DIM + h;
        float4 v = *(const float4*)src;
        u16x4 o = { f2bf(v.x * g), f2bf(v.y * g), f2bf(v.z * g), f2bf(v.w * g) };
        *(u16x4*)(Bcat + i) = o;
    } else {
        size_t i = ((size_t)(bid - 12288) * 256 + threadIdx.x) * 4;
        int hrow = (int)(i >> 11);
        int n = (int)(i & 2047);
        float sgn = 1.f;
        const float* src;
        if (n < N_DIM) src = Cre + (size_t)hrow * N_DIM + n;
        else { src = Cim + (size_t)hrow * N_DIM + (n - N_DIM); sgn = -1.f; }
        float4 v = *(const float4*)src;
        u16x4 o = { f2bf(v.x * sgn), f2bf(v.y * sgn), f2bf(v.z * sgn), f2bf(v.w * sgn) };
        *(u16x4*)(Ccat + i) = o;
    }
}

// ---------------------------------------------------------------------------
// 256x256-tile split-K bf16 NT GEMM.  Grid 256 = 16(bm) x 8(bn) x 2(ks);
// each block: C-tile 256x256 over its K-half (1024 = 16 tiles of BK=64).
// 512 thr = 8 waves (2M x 4N), per-wave OUTPUT 128x64: acc 8x4 frags
// (128 VGPR) of mfma_f32_16x16x32_bf16.
// Arithmetic intensity doubled vs 128^2: per K-tile/CU MFMA 2483cy vs
// LDS 1536 read + 512 write -> even fully serial = 55% MfmaUtil.
// LDS = A 2-buf (64KB) + B 2-buf (64KB) = 128KB -> 1 block/CU.
// Stage t+1 at tile start; one vmcnt(0)+barrier per tile (compute wall
// ~4500cy >> HBM 900cy, drain ~free).  Both-sides XOR swizzle.
// Output: bf16 partial tile at Pout (per-ks buffer).
// ---------------------------------------------------------------------------
__global__ __launch_bounds__(512, 2) void gemm_pipe(
    const u16* __restrict__ A, const u16* __restrict__ B,
    u16* __restrict__ P0, u16* __restrict__ P1)
{
    __shared__ u16 lds[65536];   // A bufs @ 0,16384 ; B bufs @ 32768,49152

    const int tid  = threadIdx.x;
    const int wave = tid >> 6, lane = tid & 63;
    // bijective XCD swizzle over 256 blocks (256 % 8 == 0)
    const int nbid = (blockIdx.x & 7) * 32 + (blockIdx.x >> 3);
    const int ks = nbid >> 7;                 // 0..1 K-half
    const int rem = nbid & 127;
    const int bm = rem >> 3;                  // 0..15
    const int bn = rem & 7;                   // 0..7
    const size_t row0 = (size_t)bm * 256;
    const size_t col0 = (size_t)bn * 256;
    const int ksBase = ks * 1024;
    u16* __restrict__ Pout = ks ? P1 : P0;

    const int wr = wave >> 2;                 // 0..1: row half (128)
    const int wc = wave & 3;                  // 0..3: col quarter (64)
    const int fr = lane & 15, fq = lane >> 4;

    // staging: thread -> row srow (0..63 within 64-row band u), chunk tid&7,
    // global source chunk pre-swizzled by row&7
    const int srow = tid >> 3;
    const int skc  = (tid & 7) ^ (srow & 7);
    const u16* aSrc = A + (row0 + srow) * KK + ksBase + skc * 8;
    const u16* bSrc = B + (col0 + srow) * KK + ksBase + skc * 8;

    // frag-read bases (u16), swizzled: slot = (kk*4+fq) ^ (fr&7)
    const int slot0 = ((fq)     ^ (fr & 7)) * 8;
    const int slot1 = ((4 + fq) ^ (fr & 7)) * 8;
    const int aRow = (wr * 128 + fr) * 64;    // + m*1024 + slot
    const int bRow = (wc * 64 + fr) * 64;     // + n*1024 + slot

    f32x4 acc[8][4] = {};

    auto STAGE_A = [&](int buf, int kt) {
#pragma unroll
        for (int u = 0; u < 4; ++u)
            gload16(aSrc + (size_t)(u * 64) * KK + kt * 64,
                    &lds[buf * 16384 + u * 4096 + wave * 512]);
    };
    auto STAGE_B = [&](int buf, int kt) {
#pragma unroll
        for (int u = 0; u < 4; ++u)
            gload16(bSrc + (size_t)(u * 64) * KK + kt * 64,
                    &lds[32768 + buf * 16384 + u * 4096 + wave * 512]);
    };

    // prologue: stage tile 0, publish
    STAGE_A(0, 0); STAGE_B(0, 0);
    asm volatile("s_waitcnt vmcnt(0)" ::: "memory");
    __builtin_amdgcn_s_barrier();

    for (int t = 0; t < NTK; ++t) {
        const u16* Ab = &lds[(t & 1) * 16384];
        const u16* Bb = &lds[32768 + (t & 1) * 16384];

        if (t + 1 < NTK) {                     // issue next tile early
            STAGE_A((t + 1) & 1, t + 1);
            STAGE_B((t + 1) & 1, t + 1);
        }

        // kstep 0 (k in [0,32) of tile)
        {
            bf16x8 fb[4];
#pragma unroll
            for (int n = 0; n < 4; ++n) fb[n] = *(const bf16x8*)&Bb[bRow + n * 1024 + slot0];
            __builtin_amdgcn_s_setprio(1);
#pragma unroll
            for (int m = 0; m < 8; ++m) {
                bf16x8 fa = *(const bf16x8*)&Ab[aRow + m * 1024 + slot0];
#pragma unroll
                for (int n = 0; n < 4; ++n)
                    acc[m][n] = __builtin_amdgcn_mfma_f32_16x16x32_bf16(
                        fa, fb[n], acc[m][n], 0, 0, 0);
            }
            __builtin_amdgcn_s_setprio(0);
        }
        // kstep 1 (k in [32,64))
        {
            bf16x8 fb[4];
#pragma unroll
            for (int n = 0; n < 4; ++n) fb[n] = *(const bf16x8*)&Bb[bRow + n * 1024 + slot1];
            __builtin_amdgcn_s_setprio(1);
#pragma unroll
            for (int m = 0; m < 8; ++m) {
                bf16x8 fa = *(const bf16x8*)&Ab[aRow + m * 1024 + slot1];
#pragma unroll
                for (int n = 0; n < 4; ++n)
                    acc[m][n] = __builtin_amdgcn_mfma_f32_16x16x32_bf16(
                        fa, fb[n], acc[m][n], 0, 0, 0);
            }
            __builtin_amdgcn_s_setprio(0);
        }

        if (t + 1 < NTK) {
            asm volatile("s_waitcnt vmcnt(0)" ::: "memory");  // next tile landed
            __builtin_amdgcn_s_barrier();
        }
    }

    // epilogue: bf16 partial store.  C/D layout col=lane&15, row=(lane>>4)*4+reg
    const int crow = (int)row0 + wr * 128 + fq * 4;
    const int ccol = (int)col0 + wc * 64 + fr;
#pragma unroll
    for (int m = 0; m < 8; ++m)
#pragma unroll
        for (int n = 0; n < 4; ++n) {
            int cc = ccol + n * 16;
#pragma unroll
            for (int j = 0; j < 4; ++j) {
                int r = crow + m * 16 + j;
                Pout[(size_t)r * N2 + cc] = f2bf(acc[m][n][j]);
            }
        }
}

// ---------------------------------------------------------------------------
// Scan (recompute scheme) over split-K partials: Bu = P0 + P1, [T,2N] bf16.
// ---------------------------------------------------------------------------
__global__ __launch_bounds__(256) void carry_pass_k(const u16* __restrict__ P0,
                                                    const u16* __restrict__ P1,
                                                    const float* __restrict__ nu,
                                                    const float* __restrict__ theta,
                                                    float* __restrict__ car) {
    int idx = blockIdx.x * 256 + threadIdx.x;   // 0 .. NCHUNK*N-1
    int chan = idx & (N_DIM - 1);
    int chunk = idx >> 10;
    float a = expf(nu[chan]), b = expf(theta[chan]);
    float m = expf(-a), s, c;
    __sincosf(b, &s, &c);
    float lr = m * c, li = m * s;
    float hr = 0.f, hi = 0.f;
    size_t base = (size_t)chunk * CHUNK * N2 + chan;
    for (int i = 0; i < CHUNK; ++i) {
        size_t p = base + (size_t)i * N2;
        float br = bf2f(P0[p]) + bf2f(P1[p]);
        float bi = bf2f(P0[p + N_DIM]) + bf2f(P1[p + N_DIM]);
        float nr = fmaf(lr, hr, fmaf(-li, hi, br));
        float ni = fmaf(lr, hi, fmaf(li, hr, bi));
        hr = nr; hi = ni;
    }
    car[(size_t)chunk * N2 + chan] = hr;
    car[(size_t)chunk * N2 + N_DIM + chan] = hi;
}

__global__ __launch_bounds__(256) void scan_carry_k(float* __restrict__ car,
                                                    const float* __restrict__ nu,
                                                    const float* __restrict__ theta) {
    __shared__ float sR[NCHUNK][65], sI[NCHUNK][65];
    int tid = threadIdx.x;
    int chan0 = blockIdx.x * 64;
    for (int i = tid; i < NCHUNK * 64; i += 256) {
        int ck = i >> 6, c = i & 63;
        sR[ck][c] = car[(size_t)ck * N2 + chan0 + c];
        sI[ck][c] = car[(size_t)ck * N2 + N_DIM + chan0 + c];
    }
    __syncthreads();
    if (tid < 64) {
        int chan = chan0 + tid;
        float a = expf(nu[chan]), b = expf(theta[chan]);
        float m = expf(-(float)CHUNK * a), s, c;
        __sincosf((float)CHUNK * b, &s, &c);
        float lr = m * c, li = m * s;
        float hr = sR[0][tid], hi = sI[0][tid];
        for (int ck = 1; ck < NCHUNK; ++ck) {
            float nr = fmaf(lr, hr, fmaf(-li, hi, sR[ck][tid]));
            float ni = fmaf(lr, hi, fmaf(li, hr, sI[ck][tid]));
            hr = nr; hi = ni;
            sR[ck][tid] = hr; sI[ck][tid] = hi;
        }
    }
    __syncthreads();
    for (int i = tid; i < NCHUNK * 64; i += 256) {
        int ck = i >> 6, c = i & 63;
        car[(size_t)ck * N2 + chan0 + c] = sR[ck][c];
        car[(size_t)ck * N2 + N_DIM + chan0 + c] = sI[ck][c];
    }
}

__global__ __launch_bounds__(256) void scan_out_k(const u16* __restrict__ P0,
                                                  const u16* __restrict__ P1,
                                                  const float* __restrict__ car,
                                                  const float* __restrict__ nu,
                                                  const float* __restrict__ theta,
                                                  u16* __restrict__ Hbf) {
    int idx = blockIdx.x * 256 + threadIdx.x;   // 0 .. NCHUNK*N-1
    int chan = idx & (N_DIM - 1);
    int chunk = idx >> 10;
    float a = expf(nu[chan]), b = expf(theta[chan]);
    float m = expf(-a), s, c;
    __sincosf(b, &s, &c);
    float lr = m * c, li = m * s;
    float hr = 0.f, hi = 0.f;
    if (chunk > 0) {
        size_t cp = (size_t)(chunk - 1) * N2 + chan;
        hr = car[cp]; hi = car[cp + N_DIM];
    }
    size_t base = (size_t)chunk * CHUNK * N2 + chan;
    for (int i = 0; i < CHUNK; ++i) {
        size_t p = base + (size_t)i * N2;
        float br = bf2f(P0[p]) + bf2f(P1[p]);
        float bi = bf2f(P0[p + N_DIM]) + bf2f(P1[p + N_DIM]);
        float nr = fmaf(lr, hr, fmaf(-li, hi, br));
        float ni = fmaf(lr, hi, fmaf(li, hr, bi));
        hr = nr; hi = ni;
        Hbf[p] = f2bf(hr);
        Hbf[p + N_DIM] = f2bf(hi);
    }
}

// ---------------------------------------------------------------------------
// Final combine: Y = f32(P0) + f32(P1) + D * bf2f(Ubf)   (pure BW, 80MB)
// ---------------------------------------------------------------------------
__global__ __launch_bounds__(256) void combine_y_k(const u16* __restrict__ P0,
                                                   const u16* __restrict__ P1,
                                                   const u16* __restrict__ Ubf,
                                                   const float* __restrict__ D,
                                                   float* __restrict__ Y) {
    size_t i = ((size_t)blockIdx.x * 256 + threadIdx.x) * 8;
    u16x8 a0 = *(const u16x8*)(P0 + i);
    u16x8 a1 = *(const u16x8*)(P1 + i);
    u16x8 uu = *(const u16x8*)(Ubf + i);
    int h = (int)(i & (size_t)(H_DIM - 1));
    float4 d0 = *(const float4*)(D + h);
    float4 d1 = *(const float4*)(D + h + 4);
    float dv[8] = { d0.x, d0.y, d0.z, d0.w, d1.x, d1.y, d1.z, d1.w };
    float y[8];
#pragma unroll
    for (int j = 0; j < 8; ++j)
        y[j] = bf2f(a0[j]) + bf2f(a1[j]) + dv[j] * bf2f(uu[j]);
    *(float4*)(Y + i)     = { y[0], y[1], y[2], y[3] };
    *(float4*)(Y + i + 4) = { y[4], y[5], y[6], y[7] };
}

extern "C" void kernel_launch(void* const* d_in, const int* in_sizes, int n_in,
                              void* d_out, int out_size, void* d_ws, size_t ws_size,
                              hipStream_t stream) {
    const float* U     = (const float*)d_in[0];   // [T,H]
    const float* nu    = (const float*)d_in[1];   // [N]
    const float* theta = (const float*)d_in[2];   // [N]
    const float* glog  = (const float*)d_in[3];   // [N]
    const float* Bre   = (const float*)d_in[4];   // [N,H]
    const float* Bim   = (const float*)d_in[5];   // [N,H]
    const float* Cre   = (const float*)d_in[6];   // [H,N]
    const float* Cim   = (const float*)d_in[7];   // [H,N]
    const float* Dp    = (const float*)d_in[8];   // [H]
    float* Y = (float*)d_out;

    u16* Ubf  = (u16*)d_ws;                             // T*H       bf16 16MB
    u16* Bcat = Ubf + (size_t)T_DIM * H_DIM;            // 2N*H      bf16  8MB
    u16* Ccat = Bcat + (size_t)N2 * H_DIM;              // H*2N      bf16  8MB
    u16* Hbf  = Ccat + (size_t)H_DIM * N2;              // T*2N      bf16 16MB
    u16* P0   = Hbf + (size_t)T_DIM * N2;               // T*2N      bf16 16MB
    u16* P1   = P0 + (size_t)T_DIM * N2;                // T*2N      bf16 16MB
    float* car = (float*)(P1 + (size_t)T_DIM * N2);     // NCHUNK*2N f32  0.5MB

    cvt_all_k<<<16384, 256, 0, stream>>>(U, Bre, Bim, glog, Cre, Cim,
                                         Ubf, Bcat, Ccat);

    // GEMM 1: Bu partials = Ubf @ Bcat^T  (split-K halves -> P0, P1)
    gemm_pipe<<<256, 512, 0, stream>>>(Ubf, Bcat, P0, P1);

    carry_pass_k<<<(NCHUNK * N_DIM) / 256, 256, 0, stream>>>(P0, P1, nu, theta, car);
    scan_carry_k<<<N_DIM / 64, 256, 0, stream>>>(car, nu, theta);
    scan_out_k<<<(NCHUNK * N_DIM) / 256, 256, 0, stream>>>(P0, P1, car, nu, theta, Hbf);

    // GEMM 2: Y partials = Hbf @ Ccat^T  (split-K halves -> P0, P1, reused)
    gemm_pipe<<<256, 512, 0, stream>>>(Hbf, Ccat, P0, P1);

    combine_y_k<<<(T_DIM * H_DIM / 8) / 256, 256, 0, stream>>>(P0, P1, Ubf, Dp, Y);
}

// Round 12
// 128.522 us; speedup vs baseline: 1.0767x; 1.0767x over previous
//
#include <hip/hip_runtime.h>
#include <math.h>

#define T_DIM 4096
#define H_DIM 2048
#define N_DIM 1024
#define N2    2048           // 2*N (concat re/im) == H
#define KK    2048           // full K of both GEMMs
#define CHUNK 64
#define NCHUNK (T_DIM / CHUNK)
#define NTK   16             // K-tiles per gemm_big block: K-half 1024 / 64
#define NT2   32             // K-tiles for gemm_kg: 2048 / 64

using u16    = unsigned short;
using u16x4  = __attribute__((ext_vector_type(4))) u16;
using u16x8  = __attribute__((ext_vector_type(8))) u16;
using bf16x8 = __attribute__((ext_vector_type(8))) short;
using f32x4  = __attribute__((ext_vector_type(4))) float;

typedef const __attribute__((address_space(1))) u16 glob_u16;
typedef __attribute__((address_space(3))) u16 lds_u16;

__device__ inline void gload16(const u16* g, u16* l) {
    __builtin_amdgcn_global_load_lds((glob_u16*)g, (lds_u16*)l, 16, 0, 0);
}

__device__ inline u16 f2bf(float x) {   // RNE fp32->bf16
    unsigned u = __builtin_bit_cast(unsigned, x);
    u += 0x7fffu + ((u >> 16) & 1u);
    return (u16)(u >> 16);
}
__device__ inline float bf2f(u16 x) {
    return __builtin_bit_cast(float, (unsigned)x << 16);
}

// Race-proof barrier (R11 post-mortem, guide rule #18):
//  - lgkmcnt(0) BEFORE s_barrier: all my ds_reads are SERVICED (data in regs)
//    before any wave can pass the barrier and DMA over the buffer — closes the
//    WAR window even if the compiler sinks the consuming MFMAs past the asm.
//  - sched_barrier(0) on both sides: nothing (incl. register-only MFMA) may
//    migrate across the sync point.
#define WAIT_BARRIER(N) do {                                                   \
    __builtin_amdgcn_sched_barrier(0);                                         \
    asm volatile("s_waitcnt vmcnt(" #N ") lgkmcnt(0)\n\ts_barrier" ::: "memory"); \
    __builtin_amdgcn_sched_barrier(0);                                         \
} while (0)

// ---------------------------------------------------------------------------
// Merged conversion kernel (R8-verified)
// ---------------------------------------------------------------------------
__global__ __launch_bounds__(256) void cvt_all_k(
    const float* __restrict__ U, const float* __restrict__ Bre,
    const float* __restrict__ Bim, const float* __restrict__ glog,
    const float* __restrict__ Cre, const float* __restrict__ Cim,
    u16* __restrict__ Ubf, u16* __restrict__ Bcat, u16* __restrict__ Ccat)
{
    int bid = blockIdx.x;
    if (bid < 8192) {
        size_t i = ((size_t)bid * 256 + threadIdx.x) * 4;
        float4 v = *(const float4*)(U + i);
        u16x4 o = { f2bf(v.x), f2bf(v.y), f2bf(v.z), f2bf(v.w) };
        *(u16x4*)(Ubf + i) = o;
    } else if (bid < 12288) {
        size_t i = ((size_t)(bid - 8192) * 256 + threadIdx.x) * 4;
        int n = (int)(i >> 11);
        size_t h = i & 2047;
        int nn = n & (N_DIM - 1);
        float g = expf(glog[nn]);
        const float* src = (n < N_DIM ? Bre : Bim) + (size_t)nn * H_DIM + h;
        float4 v = *(const float4*)src;
        u16x4 o = { f2bf(v.x * g), f2bf(v.y * g), f2bf(v.z * g), f2bf(v.w * g) };
        *(u16x4*)(Bcat + i) = o;
    } else {
        size_t i = ((size_t)(bid - 12288) * 256 + threadIdx.x) * 4;
        int hrow = (int)(i >> 11);
        int n = (int)(i & 2047);
        float sgn = 1.f;
        const float* src;
        if (n < N_DIM) src = Cre + (size_t)hrow * N_DIM + n;
        else { src = Cim + (size_t)hrow * N_DIM + (n - N_DIM); sgn = -1.f; }
        float4 v = *(const float4*)src;
        u16x4 o = { f2bf(v.x * sgn), f2bf(v.y * sgn), f2bf(v.z * sgn), f2bf(v.w * sgn) };
        *(u16x4*)(Ccat + i) = o;
    }
}

// ---------------------------------------------------------------------------
// gemm_big: 256x256 split-K bf16 NT GEMM, quadrant-phase read pipeline.
// Grid 256 = 16(bm) x 8(bn) x 2(ks).  512 thr = 8 waves (2M x 4N), per-wave
// 128x64 output.  Per K-tile (BK=64): fb[2][4] read once; 4 quadrant phases
// of 16 MFMA, fa ping-pong read ONE PHASE AHEAD.  A/B double-buffered
// (128KB LDS); stage t+1 at tile start; race-proof WAIT_BARRIER at tile end.
// Both-sides XOR swizzle.  Output: bf16 partials P0/P1.
// ---------------------------------------------------------------------------
__global__ __launch_bounds__(512, 1) void gemm_big(
    const u16* __restrict__ A, const u16* __restrict__ B,
    u16* __restrict__ P0, u16* __restrict__ P1)
{
    __shared__ u16 lds[65536];   // A bufs @ 0,16384 ; B bufs @ 32768,49152

    const int tid  = threadIdx.x;
    const int wave = tid >> 6, lane = tid & 63;
    const int nbid = (blockIdx.x & 7) * 32 + (blockIdx.x >> 3);  // bijective XCD
    const int ks = nbid >> 7;                 // 0..1 K-half
    const int rem = nbid & 127;
    const int bm = rem >> 3;                  // 0..15
    const int bn = rem & 7;                   // 0..7
    const size_t row0 = (size_t)bm * 256;
    const size_t col0 = (size_t)bn * 256;
    u16* __restrict__ Pout = ks ? P1 : P0;

    const int wr = wave >> 2;                 // 0..1: row half (128)
    const int wc = wave & 3;                  // 0..3: col quarter (64)
    const int fr = lane & 15, fq = lane >> 4;

    const int srow = tid >> 3;
    const int skc  = (tid & 7) ^ (srow & 7);
    const u16* aSrc = A + (row0 + srow) * KK + ks * 1024 + skc * 8;
    const u16* bSrc = B + (col0 + srow) * KK + ks * 1024 + skc * 8;

    const int slotk[2] = { ((fq) ^ (fr & 7)) * 8, ((4 + fq) ^ (fr & 7)) * 8 };
    const int aRow = (wr * 128 + fr) * 64;    // + m*1024 + slot
    const int bRow = (wc * 64 + fr) * 64;     // + n*1024 + slot

    f32x4 acc[8][4] = {};

    auto STAGE = [&](int buf, int kt) {
#pragma unroll
        for (int u = 0; u < 4; ++u) {
            gload16(aSrc + (size_t)(u * 64) * KK + kt * 64,
                    &lds[buf * 16384 + u * 4096 + wave * 512]);
            gload16(bSrc + (size_t)(u * 64) * KK + kt * 64,
                    &lds[32768 + buf * 16384 + u * 4096 + wave * 512]);
        }
    };

    bf16x8 fb[2][4];
    bf16x8 faF[2][2], faG[2][2];              // named ping-pong (rule #20)

    auto READ_FB = [&](const u16* Bb) {
#pragma unroll
        for (int k = 0; k < 2; ++k)
#pragma unroll
            for (int n = 0; n < 4; ++n)
                fb[k][n] = *(const bf16x8*)&Bb[bRow + n * 1024 + slotk[k]];
    };
    auto READ_FA = [&](bf16x8 (&fa)[2][2], const u16* Ab, int q) {
#pragma unroll
        for (int k = 0; k < 2; ++k)
#pragma unroll
            for (int mm = 0; mm < 2; ++mm)
                fa[k][mm] = *(const bf16x8*)&Ab[aRow + (q * 2 + mm) * 1024 + slotk[k]];
    };
    auto MFMA_Q = [&](int q, bf16x8 (&fa)[2][2]) {
        __builtin_amdgcn_s_setprio(1);
#pragma unroll
        for (int k = 0; k < 2; ++k)
#pragma unroll
            for (int mm = 0; mm < 2; ++mm)
#pragma unroll
                for (int n = 0; n < 4; ++n)
                    acc[q * 2 + mm][n] = __builtin_amdgcn_mfma_f32_16x16x32_bf16(
                        fa[k][mm], fb[k][n], acc[q * 2 + mm][n], 0, 0, 0);
        __builtin_amdgcn_s_setprio(0);
    };

    // prologue
    STAGE(0, 0);
    WAIT_BARRIER(0);
    READ_FB(&lds[32768]);
    READ_FA(faF, &lds[0], 0);

    for (int t = 0; t < NTK; ++t) {
        const u16* Ab = &lds[(t & 1) * 16384];
        const int nxt = (t & 1) ^ 1;
        if (t + 1 < NTK) STAGE(nxt, t + 1);            // 8 gloads early

        READ_FA(faG, Ab, 1);  MFMA_Q(0, faF);          // read q+1 while MFMA q
        READ_FA(faF, Ab, 2);  MFMA_Q(1, faG);
        READ_FA(faG, Ab, 3);  MFMA_Q(2, faF);
        MFMA_Q(3, faG);

        if (t + 1 < NTK) {
            WAIT_BARRIER(0);                           // t+1 landed; reads drained
            READ_FB(&lds[32768 + nxt * 16384]);
            READ_FA(faF, &lds[nxt * 16384], 0);
        }
    }

    // epilogue: bf16 partial store.  C/D: col=lane&15, row=(lane>>4)*4+reg
    const int crow = (int)row0 + wr * 128 + fq * 4;
    const int ccol = (int)col0 + wc * 64 + fr;
#pragma unroll
    for (int m = 0; m < 8; ++m)
#pragma unroll
        for (int n = 0; n < 4; ++n) {
            int cc = ccol + n * 16;
#pragma unroll
            for (int j = 0; j < 4; ++j) {
                int r = crow + m * 16 + j;
                Pout[(size_t)r * N2 + cc] = f2bf(acc[m][n][j]);
            }
        }
}

// ---------------------------------------------------------------------------
// gemm_kg: R8-verified 128^2 kg-split GEMM, full K, f32 Y with fused D*u.
// Race-proof barriers; __syncthreads in the merge.
// ---------------------------------------------------------------------------
__global__ __launch_bounds__(512, 4) void gemm_kg(
    const u16* __restrict__ A, const u16* __restrict__ B,
    float* __restrict__ Y, const float* __restrict__ D,
    const u16* __restrict__ Ubf)
{
    __shared__ u16 lds[40960];   // A bufs @ 0,8192,16384 ; B bufs @ 24576,32768

    const int tid  = threadIdx.x;
    const int wave = tid >> 6, lane = tid & 63;
    const int nbid = (blockIdx.x & 7) * 64 + (blockIdx.x >> 3);
    const int bm = nbid >> 4;                // 0..31
    const int bn = nbid & 15;                // 0..15
    const size_t row0 = (size_t)bm * 128;
    const size_t col0 = (size_t)bn * 128;
    const int kg = wave & 1;
    const int wc = (wave >> 1) & 1;
    const int wr = wave >> 2;
    const int fr = lane & 15, fq = lane >> 4;

    const int srow = wave * 16 + (lane >> 3);
    const int skc  = (lane & 7) ^ ((lane >> 3) & 7);
    const u16* aSrc = A + (row0 + srow) * KK + skc * 8;
    const u16* bSrc = B + (col0 + srow) * KK + skc * 8;
    const int stOff = wave * 1024;

    const int slot8 = ((kg * 4 + fq) ^ (fr & 7)) * 8;
    const int aOff = (wr * 64 + fr) * 64 + slot8;
    const int bOff = (wc * 64 + fr) * 64 + slot8;

    f32x4 acc[4][4] = {};

    auto STAGE_A = [&](int buf, int kt) {
        gload16(aSrc + kt * 64,          &lds[buf * 8192 + stOff]);
        gload16(aSrc + 8 * KK + kt * 64, &lds[buf * 8192 + stOff + 512]);
    };
    auto STAGE_B = [&](int buf, int kt) {
        gload16(bSrc + kt * 64,          &lds[24576 + buf * 8192 + stOff]);
        gload16(bSrc + 8 * KK + kt * 64, &lds[24576 + buf * 8192 + stOff + 512]);
    };

    bf16x8 fa[4], fb[4];
    auto READ_F = [&](const u16* Ab, const u16* Bb) {
#pragma unroll
        for (int m = 0; m < 4; ++m) fa[m] = *(const bf16x8*)&Ab[aOff + m * 1024];
#pragma unroll
        for (int n = 0; n < 4; ++n) fb[n] = *(const bf16x8*)&Bb[bOff + n * 1024];
    };

    STAGE_A(0, 0); STAGE_B(0, 0); STAGE_A(1, 1);
    WAIT_BARRIER(2);
    READ_F(&lds[0], &lds[24576]);

    int a_cur = 0;
    for (int t = 0; t < NT2; ++t) {
        if (t + 1 < NT2) STAGE_B((t + 1) & 1, t + 1);
        __builtin_amdgcn_s_setprio(1);
#pragma unroll
        for (int m = 0; m < 4; ++m)
#pragma unroll
            for (int n = 0; n < 4; ++n)
                acc[m][n] = __builtin_amdgcn_mfma_f32_16x16x32_bf16(
                    fa[m], fb[n], acc[m][n], 0, 0, 0);
        __builtin_amdgcn_s_setprio(0);
        if (t + 2 < NT2) {
            int a_nxt = a_cur + 2; if (a_nxt >= 3) a_nxt -= 3;
            STAGE_A(a_nxt, t + 2);
        }
        if (t + 1 < NT2) {
            if (t + 2 < NT2) WAIT_BARRIER(2);
            else             WAIT_BARRIER(0);
            int a_n = a_cur + 1; if (a_n == 3) a_n = 0;
            READ_F(&lds[a_n * 8192], &lds[24576 + ((t + 1) & 1) * 8192]);
        }
        ++a_cur; if (a_cur == 3) a_cur = 0;
    }

    // ---- kg-merge via LDS: full fences ----
    __syncthreads();
    const int pair = wr * 2 + wc;
    float* lf = (float*)lds;
    if (kg == 1) {
#pragma unroll
        for (int i = 0; i < 16; ++i)
            *(f32x4*)&lf[pair * 4096 + i * 256 + lane * 4] = acc[i >> 2][i & 3];
    }
    __syncthreads();
    if (kg == 0) {
#pragma unroll
        for (int i = 0; i < 16; ++i) {
            f32x4 o = *(const f32x4*)&lf[pair * 4096 + i * 256 + lane * 4];
            acc[i >> 2][i & 3] += o;
        }
        const int crow = (int)row0 + wr * 64 + fq * 4;
        const int ccol = (int)col0 + wc * 64 + fr;
        float dc[4];
#pragma unroll
        for (int n = 0; n < 4; ++n) dc[n] = D[ccol + n * 16];
#pragma unroll
        for (int m = 0; m < 4; ++m)
#pragma unroll
            for (int n = 0; n < 4; ++n) {
                int cc = ccol + n * 16;
#pragma unroll
                for (int j = 0; j < 4; ++j) {
                    int r = crow + m * 16 + j;
                    size_t p = (size_t)r * N2 + cc;
                    Y[p] = acc[m][n][j] + dc[n] * bf2f(Ubf[p]);
                }
            }
    }
}

// ---------------------------------------------------------------------------
// Scan (recompute scheme) over split-K partials: Bu = P0 + P1, [T,2N] bf16.
// ---------------------------------------------------------------------------
__global__ __launch_bounds__(256) void carry_pass_k(const u16* __restrict__ P0,
                                                    const u16* __restrict__ P1,
                                                    const float* __restrict__ nu,
                                                    const float* __restrict__ theta,
                                                    float* __restrict__ car) {
    int idx = blockIdx.x * 256 + threadIdx.x;
    int chan = idx & (N_DIM - 1);
    int chunk = idx >> 10;
    float a = expf(nu[chan]), b = expf(theta[chan]);
    float m = expf(-a), s, c;
    __sincosf(b, &s, &c);
    float lr = m * c, li = m * s;
    float hr = 0.f, hi = 0.f;
    size_t base = (size_t)chunk * CHUNK * N2 + chan;
    for (int i = 0; i < CHUNK; ++i) {
        size_t p = base + (size_t)i * N2;
        float br = bf2f(P0[p]) + bf2f(P1[p]);
        float bi = bf2f(P0[p + N_DIM]) + bf2f(P1[p + N_DIM]);
        float nr = fmaf(lr, hr, fmaf(-li, hi, br));
        float ni = fmaf(lr, hi, fmaf(li, hr, bi));
        hr = nr; hi = ni;
    }
    car[(size_t)chunk * N2 + chan] = hr;
    car[(size_t)chunk * N2 + N_DIM + chan] = hi;
}

__global__ __launch_bounds__(256) void scan_carry_k(float* __restrict__ car,
                                                    const float* __restrict__ nu,
                                                    const float* __restrict__ theta) {
    __shared__ float sR[NCHUNK][65], sI[NCHUNK][65];
    int tid = threadIdx.x;
    int chan0 = blockIdx.x * 64;
    for (int i = tid; i < NCHUNK * 64; i += 256) {
        int ck = i >> 6, c = i & 63;
        sR[ck][c] = car[(size_t)ck * N2 + chan0 + c];
        sI[ck][c] = car[(size_t)ck * N2 + N_DIM + chan0 + c];
    }
    __syncthreads();
    if (tid < 64) {
        int chan = chan0 + tid;
        float a = expf(nu[chan]), b = expf(theta[chan]);
        float m = expf(-(float)CHUNK * a), s, c;
        __sincosf((float)CHUNK * b, &s, &c);
        float lr = m * c, li = m * s;
        float hr = sR[0][tid], hi = sI[0][tid];
        for (int ck = 1; ck < NCHUNK; ++ck) {
            float nr = fmaf(lr, hr, fmaf(-li, hi, sR[ck][tid]));
            float ni = fmaf(lr, hi, fmaf(li, hr, sI[ck][tid]));
            hr = nr; hi = ni;
            sR[ck][tid] = hr; sI[ck][tid] = hi;
        }
    }
    __syncthreads();
    for (int i = tid; i < NCHUNK * 64; i += 256) {
        int ck = i >> 6, c = i & 63;
        car[(size_t)ck * N2 + chan0 + c] = sR[ck][c];
        car[(size_t)ck * N2 + N_DIM + chan0 + c] = sI[ck][c];
    }
}

__global__ __launch_bounds__(256) void scan_out_k(const u16* __restrict__ P0,
                                                  const u16* __restrict__ P1,
                                                  const float* __restrict__ car,
                                                  const float* __restrict__ nu,
                                                  const float* __restrict__ theta,
                                                  u16* __restrict__ Hbf) {
    int idx = blockIdx.x * 256 + threadIdx.x;
    int chan = idx & (N_DIM - 1);
    int chunk = idx >> 10;
    float a = expf(nu[chan]), b = expf(theta[chan]);
    float m = expf(-a), s, c;
    __sincosf(b, &s, &c);
    float lr = m * c, li = m * s;
    float hr = 0.f, hi = 0.f;
    if (chunk > 0) {
        size_t cp = (size_t)(chunk - 1) * N2 + chan;
        hr = car[cp]; hi = car[cp + N_DIM];
    }
    size_t base = (size_t)chunk * CHUNK * N2 + chan;
    for (int i = 0; i < CHUNK; ++i) {
        size_t p = base + (size_t)i * N2;
        float br = bf2f(P0[p]) + bf2f(P1[p]);
        float bi = bf2f(P0[p + N_DIM]) + bf2f(P1[p + N_DIM]);
        float nr = fmaf(lr, hr, fmaf(-li, hi, br));
        float ni = fmaf(lr, hi, fmaf(li, hr, bi));
        hr = nr; hi = ni;
        Hbf[p] = f2bf(hr);
        Hbf[p + N_DIM] = f2bf(hi);
    }
}

extern "C" void kernel_launch(void* const* d_in, const int* in_sizes, int n_in,
                              void* d_out, int out_size, void* d_ws, size_t ws_size,
                              hipStream_t stream) {
    const float* U     = (const float*)d_in[0];
    const float* nu    = (const float*)d_in[1];
    const float* theta = (const float*)d_in[2];
    const float* glog  = (const float*)d_in[3];
    const float* Bre   = (const float*)d_in[4];
    const float* Bim   = (const float*)d_in[5];
    const float* Cre   = (const float*)d_in[6];
    const float* Cim   = (const float*)d_in[7];
    const float* Dp    = (const float*)d_in[8];
    float* Y = (float*)d_out;

    u16* Ubf  = (u16*)d_ws;                             // T*H       bf16 16MB
    u16* Bcat = Ubf + (size_t)T_DIM * H_DIM;            // 2N*H      bf16  8MB
    u16* Ccat = Bcat + (size_t)N2 * H_DIM;              // H*2N      bf16  8MB
    u16* Hbf  = Ccat + (size_t)H_DIM * N2;              // T*2N      bf16 16MB
    u16* P0   = Hbf + (size_t)T_DIM * N2;               // T*2N      bf16 16MB
    u16* P1   = P0 + (size_t)T_DIM * N2;                // T*2N      bf16 16MB
    float* car = (float*)(P1 + (size_t)T_DIM * N2);     // NCHUNK*2N f32

    cvt_all_k<<<16384, 256, 0, stream>>>(U, Bre, Bim, glog, Cre, Cim,
                                         Ubf, Bcat, Ccat);

    gemm_big<<<256, 512, 0, stream>>>(Ubf, Bcat, P0, P1);

    carry_pass_k<<<(NCHUNK * N_DIM) / 256, 256, 0, stream>>>(P0, P1, nu, theta, car);
    scan_carry_k<<<N_DIM / 64, 256, 0, stream>>>(car, nu, theta);
    scan_out_k<<<(NCHUNK * N_DIM) / 256, 256, 0, stream>>>(P0, P1, car, nu, theta, Hbf);

    gemm_kg<<<512, 512, 0, stream>>>(Hbf, Ccat, Y, Dp, Ubf);
}

// Round 13
// 112.047 us; speedup vs baseline: 1.2350x; 1.1470x over previous
//
#include <hip/hip_runtime.h>
#include <math.h>

#define T_DIM 4096
#define H_DIM 2048
#define N_DIM 1024
#define N2    2048           // 2*N (interleaved re/im) == H
#define KK    2048           // full K of both GEMMs
#define CHUNK 64
#define NCHUNK (T_DIM / CHUNK)
#define NT2   32             // K-tiles: 2048 / 64

using u16    = unsigned short;
using u16x4  = __attribute__((ext_vector_type(4))) u16;
using bf16x8 = __attribute__((ext_vector_type(8))) short;
using f32x4  = __attribute__((ext_vector_type(4))) float;

typedef const __attribute__((address_space(1))) u16 glob_u16;
typedef __attribute__((address_space(3))) u16 lds_u16;

__device__ inline void gload16(const u16* g, u16* l) {
    __builtin_amdgcn_global_load_lds((glob_u16*)g, (lds_u16*)l, 16, 0, 0);
}

__device__ inline u16 f2bf(float x) {   // RNE fp32->bf16
    unsigned u = __builtin_bit_cast(unsigned, x);
    u += 0x7fffu + ((u >> 16) & 1u);
    return (u16)(u >> 16);
}
__device__ inline float bf2f(u16 x) {
    return __builtin_bit_cast(float, (unsigned)x << 16);
}

// Race-proof barrier (R12-verified): lgkmcnt(0) drained BEFORE s_barrier so
// every wave's ds_reads are serviced before anyone can DMA over the buffer.
#define WAIT_BARRIER(N) \
    asm volatile("s_waitcnt vmcnt(" #N ") lgkmcnt(0)\n\ts_barrier" ::: "memory")

// ---------------------------------------------------------------------------
// Merged conversion.  INTERLEAVED layouts:
//   Bcat row 2n = gamma*B_re[n], row 2n+1 = gamma*B_im[n]       [2N][H]
//   Ccat[h][2n] = C_re[h][n],   [h][2n+1] = -C_im[h][n]         [H][2N]
// ---------------------------------------------------------------------------
__global__ __launch_bounds__(256) void cvt_all_k(
    const float* __restrict__ U, const float* __restrict__ Bre,
    const float* __restrict__ Bim, const float* __restrict__ glog,
    const float* __restrict__ Cre, const float* __restrict__ Cim,
    u16* __restrict__ Ubf, u16* __restrict__ Bcat, u16* __restrict__ Ccat)
{
    int bid = blockIdx.x;
    if (bid < 8192) {
        size_t i = ((size_t)bid * 256 + threadIdx.x) * 4;
        float4 v = *(const float4*)(U + i);
        u16x4 o = { f2bf(v.x), f2bf(v.y), f2bf(v.z), f2bf(v.w) };
        *(u16x4*)(Ubf + i) = o;
    } else if (bid < 12288) {
        size_t i = ((size_t)(bid - 8192) * 256 + threadIdx.x) * 4;
        int rr = (int)(i >> 11);          // row in Bcat [0,2048)
        size_t h = i & 2047;
        int chan = rr >> 1, part = rr & 1;
        float g = expf(glog[chan]);
        const float* src = (part ? Bim : Bre) + (size_t)chan * H_DIM + h;
        float4 v = *(const float4*)src;
        u16x4 o = { f2bf(v.x * g), f2bf(v.y * g), f2bf(v.z * g), f2bf(v.w * g) };
        *(u16x4*)(Bcat + i) = o;
    } else {
        size_t i = ((size_t)(bid - 12288) * 256 + threadIdx.x) * 4;
        int hrow = (int)(i >> 11);
        int n2 = (int)(i & 2047);         // multiple of 4
        int c0 = n2 >> 1;
        float2 re = *(const float2*)(Cre + (size_t)hrow * N_DIM + c0);
        float2 im = *(const float2*)(Cim + (size_t)hrow * N_DIM + c0);
        u16x4 o = { f2bf(re.x), f2bf(-im.x), f2bf(re.y), f2bf(-im.y) };
        *(u16x4*)(Ccat + i) = o;
    }
}

// ---------------------------------------------------------------------------
// gemm_pipe: R8-verified 128^2 kg-split GEMM, full K.  512 thr = 8 waves
// (wr2 x wc2 x kg2), per-wave 64x64 over its K-half; 16 waves/CU.
// LDS = A 3-buf + B 2-buf = 80KB -> 2 blocks/CU.  Race-proof WAIT_BARRIER.
// kg-merge via LDS (full __syncthreads fences).
// EPI=0: store bf16 Bu; then FUSED CARRY: dump tile to LDS, 128 workers run
//        the 64-step complex scan per (band, channel) -> car (saves a kernel).
// EPI=1: store f32 Y = acc + D[col]*bf2f(Ubf).
// ---------------------------------------------------------------------------
template <int EPI>
__global__ __launch_bounds__(512, 4) void gemm_pipe(
    const u16* __restrict__ A, const u16* __restrict__ B,
    void* __restrict__ Cout, const float* __restrict__ D,
    const u16* __restrict__ Ubf, const float* __restrict__ nu,
    const float* __restrict__ theta, float2* __restrict__ car2)
{
    __shared__ u16 lds[40960];   // A bufs @ 0,8192,16384 ; B bufs @ 24576,32768

    const int tid  = threadIdx.x;
    const int wave = tid >> 6, lane = tid & 63;
    const int nbid = (blockIdx.x & 7) * 64 + (blockIdx.x >> 3);
    const int bm = nbid >> 4;                // 0..31
    const int bn = nbid & 15;                // 0..15
    const size_t row0 = (size_t)bm * 128;
    const size_t col0 = (size_t)bn * 128;
    const int kg = wave & 1;
    const int wc = (wave >> 1) & 1;
    const int wr = wave >> 2;
    const int fr = lane & 15, fq = lane >> 4;

    const int srow = wave * 16 + (lane >> 3);
    const int skc  = (lane & 7) ^ ((lane >> 3) & 7);
    const u16* aSrc = A + (row0 + srow) * KK + skc * 8;
    const u16* bSrc = B + (col0 + srow) * KK + skc * 8;
    const int stOff = wave * 1024;

    const int slot8 = ((kg * 4 + fq) ^ (fr & 7)) * 8;
    const int aOff = (wr * 64 + fr) * 64 + slot8;
    const int bOff = (wc * 64 + fr) * 64 + slot8;

    f32x4 acc[4][4] = {};

    auto STAGE_A = [&](int buf, int kt) {
        gload16(aSrc + kt * 64,          &lds[buf * 8192 + stOff]);
        gload16(aSrc + 8 * KK + kt * 64, &lds[buf * 8192 + stOff + 512]);
    };
    auto STAGE_B = [&](int buf, int kt) {
        gload16(bSrc + kt * 64,          &lds[24576 + buf * 8192 + stOff]);
        gload16(bSrc + 8 * KK + kt * 64, &lds[24576 + buf * 8192 + stOff + 512]);
    };

    bf16x8 fa[4], fb[4];
    auto READ_F = [&](const u16* Ab, const u16* Bb) {
#pragma unroll
        for (int m = 0; m < 4; ++m) fa[m] = *(const bf16x8*)&Ab[aOff + m * 1024];
#pragma unroll
        for (int n = 0; n < 4; ++n) fb[n] = *(const bf16x8*)&Bb[bOff + n * 1024];
    };

    STAGE_A(0, 0); STAGE_B(0, 0); STAGE_A(1, 1);
    WAIT_BARRIER(2);
    READ_F(&lds[0], &lds[24576]);

    int a_cur = 0;
    for (int t = 0; t < NT2; ++t) {
        if (t + 1 < NT2) STAGE_B((t + 1) & 1, t + 1);
        __builtin_amdgcn_s_setprio(1);
#pragma unroll
        for (int m = 0; m < 4; ++m)
#pragma unroll
            for (int n = 0; n < 4; ++n)
                acc[m][n] = __builtin_amdgcn_mfma_f32_16x16x32_bf16(
                    fa[m], fb[n], acc[m][n], 0, 0, 0);
        __builtin_amdgcn_s_setprio(0);
        if (t + 2 < NT2) {
            int a_nxt = a_cur + 2; if (a_nxt >= 3) a_nxt -= 3;
            STAGE_A(a_nxt, t + 2);
        }
        if (t + 1 < NT2) {
            if (t + 2 < NT2) WAIT_BARRIER(2);
            else             WAIT_BARRIER(0);
            int a_n = a_cur + 1; if (a_n == 3) a_n = 0;
            READ_F(&lds[a_n * 8192], &lds[24576 + ((t + 1) & 1) * 8192]);
        }
        ++a_cur; if (a_cur == 3) a_cur = 0;
    }

    // ---- kg-merge via LDS (full fences) ----
    __syncthreads();
    const int pair = wr * 2 + wc;
    float* lf = (float*)lds;
    if (kg == 1) {
#pragma unroll
        for (int i = 0; i < 16; ++i)
            *(f32x4*)&lf[pair * 4096 + i * 256 + lane * 4] = acc[i >> 2][i & 3];
    }
    __syncthreads();
    if (kg == 0) {
#pragma unroll
        for (int i = 0; i < 16; ++i) {
            f32x4 o = *(const f32x4*)&lf[pair * 4096 + i * 256 + lane * 4];
            acc[i >> 2][i & 3] += o;
        }
    }
    const int crow = (int)row0 + wr * 64 + fq * 4;
    const int ccol = (int)col0 + wc * 64 + fr;

    if constexpr (EPI) {
        if (kg == 0) {
            float dc[4];
#pragma unroll
            for (int n = 0; n < 4; ++n) dc[n] = D[ccol + n * 16];
#pragma unroll
            for (int m = 0; m < 4; ++m)
#pragma unroll
                for (int n = 0; n < 4; ++n) {
                    int cc = ccol + n * 16;
#pragma unroll
                    for (int j = 0; j < 4; ++j) {
                        int r = crow + m * 16 + j;
                        size_t p = (size_t)r * N2 + cc;
                        ((float*)Cout)[p] = acc[m][n][j] + dc[n] * bf2f(Ubf[p]);
                    }
                }
        }
    } else {
        // store bf16 Bu to global AND to LDS tile [128][128] for fused carry
        __syncthreads();                       // merge reads done; lds reusable
        u16* tile = lds;                       // 16384 u16 = 32KB
        if (kg == 0) {
#pragma unroll
            for (int m = 0; m < 4; ++m)
#pragma unroll
                for (int n = 0; n < 4; ++n) {
                    int cc = ccol + n * 16;
                    int lc = (wc * 64 + fr) + n * 16;        // col in tile
#pragma unroll
                    for (int j = 0; j < 4; ++j) {
                        int r = crow + m * 16 + j;
                        int lr = (wr * 64 + fq * 4 + j) + m * 16;  // row in tile
                        u16 v = f2bf(acc[m][n][j]);
                        ((u16*)Cout)[(size_t)r * N2 + cc] = v;
                        tile[lr * 128 + lc] = v;
                    }
                }
        }
        __syncthreads();                       // tile complete
        // fused carry: 128 workers = 2 bands x 64 channels
        if (tid < 128) {
            int band = tid >> 6;               // 0..1 (chunk within block)
            int ch   = tid & 63;               // channel within block
            int chan = ((int)col0 >> 1) + ch;  // global channel
            float a = expf(nu[chan]), b = expf(theta[chan]);
            float mm = expf(-a), s, c;
            __sincosf(b, &s, &c);
            float lr_ = mm * c, li_ = mm * s;
            float hr = 0.f, hi = 0.f;
            const u16* rowp = &tile[band * 64 * 128 + 2 * ch];
            for (int i = 0; i < CHUNK; ++i) {
                unsigned pr = *(const unsigned*)(rowp + i * 128);
                float br = bf2f((u16)(pr & 0xffff));
                float bi = bf2f((u16)(pr >> 16));
                float nr = fmaf(lr_, hr, fmaf(-li_, hi, br));
                float ni = fmaf(lr_, hi, fmaf(li_, hr, bi));
                hr = nr; hi = ni;
            }
            int ckG = bm * 2 + band;
            car2[(size_t)ckG * N_DIM + chan] = make_float2(hr, hi);
        }
    }
}

// ---------------------------------------------------------------------------
// pass 2: combine carries across chunks (lambda^CHUNK closed form), float2
// ---------------------------------------------------------------------------
__global__ __launch_bounds__(256) void scan_carry_k(float2* __restrict__ car2,
                                                    const float* __restrict__ nu,
                                                    const float* __restrict__ theta) {
    __shared__ float2 sc[NCHUNK][65];
    int tid = threadIdx.x;
    int chan0 = blockIdx.x * 64;
    for (int i = tid; i < NCHUNK * 64; i += 256) {
        int ck = i >> 6, c = i & 63;
        sc[ck][c] = car2[(size_t)ck * N_DIM + chan0 + c];
    }
    __syncthreads();
    if (tid < 64) {
        int chan = chan0 + tid;
        float a = expf(nu[chan]), b = expf(theta[chan]);
        float m = expf(-(float)CHUNK * a), s, c;
        __sincosf((float)CHUNK * b, &s, &c);
        float lr = m * c, li = m * s;
        float2 h = sc[0][tid];
        for (int ck = 1; ck < NCHUNK; ++ck) {
            float2 v = sc[ck][tid];
            float nr = fmaf(lr, h.x, fmaf(-li, h.y, v.x));
            float ni = fmaf(lr, h.y, fmaf(li, h.x, v.y));
            h.x = nr; h.y = ni;
            sc[ck][tid] = h;
        }
    }
    __syncthreads();
    for (int i = tid; i < NCHUNK * 64; i += 256) {
        int ck = i >> 6, c = i & 63;
        car2[(size_t)ck * N_DIM + chan0 + c] = sc[ck][c];
    }
}

// ---------------------------------------------------------------------------
// pass 3: recompute local scan seeded with combined carry, write bf16 h.
// Interleaved pairs: one u32 load/store per (t, channel).
// ---------------------------------------------------------------------------
__global__ __launch_bounds__(256) void scan_out_k(const u16* __restrict__ Bu,
                                                  const float2* __restrict__ car2,
                                                  const float* __restrict__ nu,
                                                  const float* __restrict__ theta,
                                                  u16* __restrict__ Hbf) {
    int idx = blockIdx.x * 256 + threadIdx.x;   // 0 .. NCHUNK*N-1
    int chan = idx & (N_DIM - 1);
    int chunk = idx >> 10;
    float a = expf(nu[chan]), b = expf(theta[chan]);
    float m = expf(-a), s, c;
    __sincosf(b, &s, &c);
    float lr = m * c, li = m * s;
    float hr = 0.f, hi = 0.f;
    if (chunk > 0) {
        float2 h0 = car2[(size_t)(chunk - 1) * N_DIM + chan];
        hr = h0.x; hi = h0.y;
    }
    size_t base = (size_t)chunk * CHUNK * N2 + 2 * chan;
    for (int i = 0; i < CHUNK; ++i) {
        size_t p = base + (size_t)i * N2;
        unsigned pr = *(const unsigned*)(Bu + p);
        float br = bf2f((u16)(pr & 0xffff));
        float bi = bf2f((u16)(pr >> 16));
        float nr = fmaf(lr, hr, fmaf(-li, hi, br));
        float ni = fmaf(lr, hi, fmaf(li, hr, bi));
        hr = nr; hi = ni;
        *(unsigned*)(Hbf + p) = (unsigned)f2bf(hr) | ((unsigned)f2bf(hi) << 16);
    }
}

extern "C" void kernel_launch(void* const* d_in, const int* in_sizes, int n_in,
                              void* d_out, int out_size, void* d_ws, size_t ws_size,
                              hipStream_t stream) {
    const float* U     = (const float*)d_in[0];
    const float* nu    = (const float*)d_in[1];
    const float* theta = (const float*)d_in[2];
    const float* glog  = (const float*)d_in[3];
    const float* Bre   = (const float*)d_in[4];
    const float* Bim   = (const float*)d_in[5];
    const float* Cre   = (const float*)d_in[6];
    const float* Cim   = (const float*)d_in[7];
    const float* Dp    = (const float*)d_in[8];
    float* Y = (float*)d_out;

    u16* Ubf  = (u16*)d_ws;                             // T*H       bf16 16MB
    u16* Bcat = Ubf + (size_t)T_DIM * H_DIM;            // 2N*H      bf16  8MB
    u16* Ccat = Bcat + (size_t)N2 * H_DIM;              // H*2N      bf16  8MB
    u16* Hbf  = Ccat + (size_t)H_DIM * N2;              // T*2N      bf16 16MB
    u16* Bu   = Hbf + (size_t)T_DIM * N2;               // T*2N      bf16 16MB
    float2* car2 = (float2*)(Bu + (size_t)T_DIM * N2);  // NCHUNK*N  f2  0.5MB

    cvt_all_k<<<16384, 256, 0, stream>>>(U, Bre, Bim, glog, Cre, Cim,
                                         Ubf, Bcat, Ccat);

    gemm_pipe<0><<<512, 512, 0, stream>>>(Ubf, Bcat, (void*)Bu, nullptr,
                                          nullptr, nu, theta, car2);

    scan_carry_k<<<N_DIM / 64, 256, 0, stream>>>(car2, nu, theta);
    scan_out_k<<<(NCHUNK * N_DIM) / 256, 256, 0, stream>>>(Bu, car2, nu, theta, Hbf);

    gemm_pipe<1><<<512, 512, 0, stream>>>(Hbf, Ccat, (void*)Y, Dp,
                                          Ubf, nullptr, nullptr, nullptr);
}